// Round 11
// baseline (558.821 us; speedup 1.0000x reference)
//
#include <hip/hip_runtime.h>

// CRF log-likelihood: B=512, T=1024, K=64. out = mean_b(Z[b]-gold[b]).
//
// R10: fwd chain rebuilt around v_readlane broadcast — NO LDS in fwd at all.
// Lesson from R9: 512 blocks -> 2 waves/CU co-resident; HW overlaps their
// serial chains for free (R2's 288us == one chain). fwd2's in-wave pairing
// (393us) destroyed that. So: 1 seq/wave, grid 512, and shorten the chain:
//   v[k] = sum_j E[k][j] * readlane(w, j)   (64 readlane + 32 pk-FMA, VALU-only)
// No ds_write/ds_read/120cy LDS latency on the critical path. Renorm ref
// w[3] is one of the readlanes -> renorm is ~3 extra instrs, every step.
//   w_new = v * (e^h * rcp(w3_old)),  O -= log(rc) in f64 side chain
// (exact bookkeeping: logs the factor actually applied). Same math as the
// absmax-0.0 R9 kernel; only the broadcast mechanism changed.

#define PAD_IDX 0
#define SOS_IDX 1
#define EOS_IDX 2
constexpr int B = 512, T = 1024, K = 64;

typedef float v2f __attribute__((ext_vector_type(2)));

__device__ __forceinline__ float RL(float v, int lane) {
  return __uint_as_float(__builtin_amdgcn_readlane(__float_as_uint(v), lane));
}

// y0 may be int64 (reference dtype) or int32 (JAX x64-off). Little-endian:
// y0[1]==0 iff int64 (hi word of SOS); int32 data has y0[1]>=3.
__device__ __forceinline__ int yval(const int* __restrict__ y, int i, int sh) {
  return y[i << sh];
}

__global__ __launch_bounds__(1024) void gold_len_kernel(
    const float* __restrict__ h, const float* __restrict__ trans,
    const int* __restrict__ y0, double* __restrict__ goldOut,
    int* __restrict__ lenOut)
{
  const int b = blockIdx.x, tid = threadIdx.x;      // tid == t
  const float* hb = h + (size_t)b * T * K;
  const int sh = (y0[1] == 0) ? 1 : 0;
  const int* yb = y0 + (((size_t)b * (T + 1)) << sh);

  int ycur = yval(yb, tid + 1, sh);
  double acc = 0.0;
  int mpos = 0;
  if (ycur > PAD_IDX) {                             // pads are a suffix
    int yprev = yval(yb, tid, sh);
    acc = (double)(hb[(size_t)tid * K + ycur] + trans[ycur * K + yprev]);
    mpos = tid + 1;
  }
  #pragma unroll
  for (int off = 32; off > 0; off >>= 1) {
    acc += __shfl_down(acc, off, 64);
    mpos = max(mpos, __shfl_down(mpos, off, 64));
  }
  __shared__ double sa[16];
  __shared__ int sm[16];
  if ((tid & 63) == 0) { sa[tid >> 6] = acc; sm[tid >> 6] = mpos; }
  __syncthreads();
  if (tid < 64) {
    double a = (tid < 16) ? sa[tid] : 0.0;
    int mp = (tid < 16) ? sm[tid] : 0;
    #pragma unroll
    for (int off = 8; off > 0; off >>= 1) {
      a += __shfl_down(a, off, 64);
      mp = max(mp, __shfl_down(mp, off, 64));
    }
    if (tid == 0) {
      int last = yval(yb, mp, sh);                  // last real token
      goldOut[b] = a + (double)trans[EOS_IDX * K + last];
      lenOut[b] = mp;
    }
  }
}

__global__ __launch_bounds__(64) void fwd_rl_kernel(
    const float* __restrict__ h, const float* __restrict__ trans,
    const int* __restrict__ lenIn, double* __restrict__ ZdOut)
{
  const int k = threadIdx.x;                        // lane = state
  const int b = blockIdx.x;
  const float* hb = h + (size_t)b * T * K;
  const int len = lenIn[b];

  // E row k as 32 float2 in VGPRs; exp(-10000)=0 reproduces masking.
  v2f E2[32];
  #pragma unroll
  for (int j = 0; j < 32; ++j) {
    E2[j].x = __expf(trans[k * K + 2 * j]);
    E2[j].y = __expf(trans[k * K + 2 * j + 1]);
  }
  const float eEOS = __expf(trans[EOS_IDX * K + k]);

  float w = (k == SOS_IDX) ? 1.0f : 0.0f;           // exp-space state (scaled)
  double O = 0.0;                                   // f64 log-offset (side chain)

  auto STEP = [&](float f) {
    v2f a0 = {0, 0}, a1 = {0, 0}, a2 = {0, 0}, a3 = {0, 0};
    float s3 = 0.0f;                                // w[3] falls out of the bcast
    #pragma unroll
    for (int j = 0; j < 32; ++j) {                  // 64 readlane + 32 pk-FMA
      v2f s;
      s.x = RL(w, 2 * j);
      s.y = RL(w, 2 * j + 1);
      if (j == 1) s3 = s.y;                         // lane 3 (compile-time select)
      if ((j & 3) == 0)      a0 = E2[j] * s + a0;
      else if ((j & 3) == 1) a1 = E2[j] * s + a1;
      else if ((j & 3) == 2) a2 = E2[j] * s + a2;
      else                   a3 = E2[j] * s + a3;
    }
    v2f sv = (a0 + a1) + (a2 + a3);
    float v = sv.x + sv.y;
    // Renorm by old w[3] (first live state; lanes 0..2 dead/special).
    float rc = (s3 > 0.0f) ? __builtin_amdgcn_rcpf(s3) : 1.0f;
    O -= (double)__logf(rc);                        // off-chain, exact bookkeeping
    w = v * (f * rc);
  };

  const int lm1 = len - 1;
  auto hload = [&](int t) { return hb[(size_t)min(t, lm1) * K + k]; };

  // 4-deep h prefetch; exp(h) computed off the serial chain.
  float p0 = hload(0), p1 = hload(1), p2 = hload(2), p3 = hload(3);
  int t = 0;
  for (; t + 4 <= len; t += 4) {
    float n0 = hload(t + 4), n1 = hload(t + 5), n2 = hload(t + 6), n3 = hload(t + 7);
    STEP(__expf(p0)); STEP(__expf(p1)); STEP(__expf(p2)); STEP(__expf(p3));
    p0 = n0; p1 = n1; p2 = n2; p3 = n3;
  }
  for (; t < len; ++t) STEP(__expf(hb[(size_t)t * K + k]));

  // Z = O + log( sum_k w[k] * exp(trans[EOS,k]) )
  float s = w * eEOS;
  #pragma unroll
  for (int off = 32; off > 0; off >>= 1) s += __shfl_xor(s, off, 64);
  if (k == 0) ZdOut[b] = O + (double)__logf(s);
}

__global__ __launch_bounds__(512) void reduce_kernel(
    const double* __restrict__ Zd, const double* __restrict__ goldIn,
    float* __restrict__ out)
{
  __shared__ double sdata[8];
  const int tid = threadIdx.x;
  double v = Zd[tid] - goldIn[tid];
  #pragma unroll
  for (int off = 32; off > 0; off >>= 1) v += __shfl_down(v, off, 64);
  if ((tid & 63) == 0) sdata[tid >> 6] = v;
  __syncthreads();
  if (tid == 0) {
    double s = 0.0;
    #pragma unroll
    for (int i = 0; i < 8; ++i) s += sdata[i];
    out[0] = (float)(s / (double)B);
  }
}

extern "C" void kernel_launch(void* const* d_in, const int* in_sizes, int n_in,
                              void* d_out, int out_size, void* d_ws, size_t ws_size,
                              hipStream_t stream) {
  const float* h = (const float*)d_in[0];
  const float* trans = (const float*)d_in[1];
  const int* y0 = (const int*)d_in[2];   // int32 or int64; detected in-kernel

  double* Zd = (double*)d_ws;            // [B]
  double* gold = Zd + B;                 // [B]
  int* len = (int*)(gold + B);           // [B]

  gold_len_kernel<<<B, 1024, 0, stream>>>(h, trans, y0, gold, len);
  fwd_rl_kernel<<<B, 64, 0, stream>>>(h, trans, len, Zd);
  reduce_kernel<<<1, 512, 0, stream>>>(Zd, gold, (float*)d_out);
}